// Round 1
// baseline (308.141 us; speedup 1.0000x reference)
//
#include <hip/hip_runtime.h>

#define BATCH 4096
#define LQ 30
#define LD 128
#define EMB 50
#define DPAD 52
#define NROW 158
#define KN 21
#define EM1 0.36787944117144233f

__device__ __forceinline__ float grp16_sum(float v) {
  v += __shfl_xor(v, 8);
  v += __shfl_xor(v, 4);
  v += __shfl_xor(v, 2);
  v += __shfl_xor(v, 1);
  return v;
}

__global__ __launch_bounds__(256, 4) void knrm_pair_kernel(
    const int* __restrict__ q1, const int* __restrict__ d1,
    const int* __restrict__ q2, const int* __restrict__ d2,
    const float* __restrict__ emb, const float* __restrict__ mlp_w,
    const float* __restrict__ mlp_b, float* __restrict__ logits)
{
  __shared__ float smem[NROW][DPAD];   // rows 0..29 = query, 30..157 = doc
  __shared__ int toks[NROW];
  __shared__ float red[16];

  const int b = blockIdx.x;
  const int pair = blockIdx.y;
  const int tid = threadIdx.x;
  const int* __restrict__ qp = pair ? q2 : q1;
  const int* __restrict__ dp = pair ? d2 : d1;

  // token ids for all 158 rows
  if (tid < NROW)
    toks[tid] = (tid < LQ) ? qp[b * LQ + tid] : dp[b * LD + (tid - LQ)];
  __syncthreads();

  // bulk gather raw embedding rows into LDS (coalesced within rows)
  for (int i = tid; i < NROW * DPAD; i += 256) {
    int row = i / DPAD;
    int dim = i - row * DPAD;
    float v = 0.0f;
    if (dim < EMB) v = emb[toks[row] * EMB + dim];
    ((float*)smem)[i] = v;
  }
  __syncthreads();

  // normalize rows in-place: 16-lane group per row, 16 rows / iteration
  {
    const int lg = tid & 15;
    const int g = tid >> 4;   // 0..15
    #pragma unroll
    for (int it = 0; it < 10; ++it) {
      int row = it * 16 + g;
      float4 v4 = make_float4(0.f, 0.f, 0.f, 0.f);
      bool ok = (row < NROW) && (lg < 13);
      if (ok) v4 = *(const float4*)&smem[row][lg * 4];
      float ss = v4.x*v4.x + v4.y*v4.y + v4.z*v4.z + v4.w*v4.w;
      ss = grp16_sum(ss);
      float scale = 1.0f / fmaxf(sqrtf(ss), 1e-12f);
      if (ok) {
        v4.x *= scale; v4.y *= scale; v4.z *= scale; v4.w *= scale;
        *(float4*)&smem[row][lg * 4] = v4;
      }
    }
  }
  __syncthreads();

  // phase 2: each 16-lane group owns one q-row; lane lg covers docs lg+16j
  const int lg = tid & 15;
  const int grp = (tid >> 4) & 3;
  const int wv = tid >> 6;
  float part = 0.0f;

  for (int it = 0; it < 2; ++it) {
    const int qrow = it * 16 + wv * 4 + grp;
    const bool active = (qrow < LQ);
    const int r = active ? qrow : 0;
    float4 eqr[13];
    #pragma unroll
    for (int i = 0; i < 13; ++i) eqr[i] = *(const float4*)&smem[r][i * 4];

    float acc[KN];
    #pragma unroll
    for (int k = 0; k < KN; ++k) acc[k] = 0.0f;

    #pragma unroll 2
    for (int j = 0; j < 8; ++j) {
      const float4* __restrict__ edr = (const float4*)&smem[LQ + lg + j * 16][0];
      float4 s4 = make_float4(0.f, 0.f, 0.f, 0.f);
      #pragma unroll
      for (int i = 0; i < 13; ++i) {
        float4 e = edr[i];
        s4.x = fmaf(eqr[i].x, e.x, s4.x);
        s4.y = fmaf(eqr[i].y, e.y, s4.y);
        s4.z = fmaf(eqr[i].z, e.z, s4.z);
        s4.w = fmaf(eqr[i].w, e.w, s4.w);
      }
      const float x = (s4.x + s4.y) + (s4.z + s4.w);

      // 21 RBF kernels: two-sided running-product from center kernel (mu=0.05)
      const float t = x - 0.05f;
      float v = __expf(-50.0f * t * t);       // center kernel value, no underflow
      const float E = __expf(10.0f * x);
      const float Fv = __expf(-10.0f * x);
      acc[10] += v;
      float vu = v, ru = E * EM1;             // ratio v11/v10 = E*e^-1
      #pragma unroll
      for (int k = 11; k <= 19; ++k) { vu *= ru; acc[k] += vu; ru *= EM1; }
      float vd = v, rd = Fv;                  // ratio v9/v10 = F
      #pragma unroll
      for (int k = 9; k >= 0; --k) { vd *= rd; acc[k] += vd; rd *= EM1; }
      const float u = x - 1.0f;               // exact-match kernel mu=1, s=0.001
      acc[20] += __expf(-500000.0f * u * u);
    }

    // butterfly-reduce the 21 sums over the 16 lanes of the group
    #pragma unroll
    for (int k = 0; k < KN; ++k) {
      acc[k] += __shfl_xor(acc[k], 8);
      acc[k] += __shfl_xor(acc[k], 4);
      acc[k] += __shfl_xor(acc[k], 2);
      acc[k] += __shfl_xor(acc[k], 1);
    }

    if (active) {
      float rowsum = 0.0f;
      #pragma unroll
      for (int k = 0; k < KN; ++k)
        rowsum = fmaf(mlp_w[k], __logf(1.0f + acc[k]), rowsum);
      part += rowsum;
    }
  }

  if (lg == 0) red[tid >> 4] = part;   // part identical across the 16 lanes
  __syncthreads();
  if (tid == 0) {
    float tot = 0.0f;
    #pragma unroll
    for (int i = 0; i < 16; ++i) tot += red[i];
    logits[pair * BATCH + b] = tot + mlp_b[0];
  }
}

__global__ void knrm_combine_kernel(const float* __restrict__ logits,
                                    float* __restrict__ out) {
  int i = blockIdx.x * 256 + threadIdx.x;
  if (i < BATCH) {
    float z = logits[i] - logits[BATCH + i];
    out[i] = 1.0f / (1.0f + __expf(-z));
  }
}

extern "C" void kernel_launch(void* const* d_in, const int* in_sizes, int n_in,
                              void* d_out, int out_size, void* d_ws, size_t ws_size,
                              hipStream_t stream) {
  const int* q1 = (const int*)d_in[0];
  const int* d1 = (const int*)d_in[1];
  const int* q2 = (const int*)d_in[2];
  const int* d2 = (const int*)d_in[3];
  const float* emb = (const float*)d_in[4];
  const float* mlp_w = (const float*)d_in[5];
  const float* mlp_b = (const float*)d_in[6];
  float* out = (float*)d_out;
  float* logits = (float*)d_ws;   // 2*BATCH floats of scratch

  dim3 grid(BATCH, 2);
  knrm_pair_kernel<<<grid, 256, 0, stream>>>(q1, d1, q2, d2, emb, mlp_w, mlp_b, logits);
  knrm_combine_kernel<<<(BATCH + 255) / 256, 256, 0, stream>>>(logits, out);
}

// Round 2
// 203.485 us; speedup vs baseline: 1.5143x; 1.5143x over previous
//
#include <hip/hip_runtime.h>
#include <hip/hip_bf16.h>

#define BATCH 4096
#define LQ 30
#define LD 128
#define EMB 50
#define KPAD 72        // bf16 elems per row: 64 used (k 50..63 zero), 8 pad for banks
#define ROWS 160       // rows 0..31 = queries (30 real), 32..159 = docs
#define KN 21
#define EM1 0.36787944117144233f

typedef __attribute__((ext_vector_type(8))) short short8;
typedef __attribute__((ext_vector_type(4))) float f32x4;

__device__ __forceinline__ float grp16_sum(float v) {
  v += __shfl_xor(v, 8);
  v += __shfl_xor(v, 4);
  v += __shfl_xor(v, 2);
  v += __shfl_xor(v, 1);
  return v;
}

__global__ __launch_bounds__(256, 3) void knrm_pair_kernel(
    const int* __restrict__ q1, const int* __restrict__ d1,
    const int* __restrict__ q2, const int* __restrict__ d2,
    const float* __restrict__ emb, const float* __restrict__ mlp_w,
    const float* __restrict__ mlp_b, float* __restrict__ logits)
{
  __shared__ __hip_bfloat16 shi[ROWS][KPAD];
  __shared__ __hip_bfloat16 slo[ROWS][KPAD];
  __shared__ int toks[ROWS];
  __shared__ float redbuf[2][16][KN];
  __shared__ float qpart[2];

  const int b = blockIdx.x;
  const int pair = blockIdx.y;
  const int tid = threadIdx.x;
  const int* __restrict__ qp = pair ? q2 : q1;
  const int* __restrict__ dp = pair ? d2 : d1;

  // ---- token ids: rows 0..29 query, 30..31 invalid pad, 32..159 doc ----
  if (tid < ROWS) {
    int t = -1;
    if (tid < LQ) t = qp[b * LQ + tid];
    else if (tid >= 32) t = dp[b * LD + (tid - 32)];
    toks[tid] = t;
  }
  __syncthreads();

  // ---- gather + L2-normalize + hi/lo bf16 split into LDS ----
  {
    const int lg = tid & 15;
    const int g = tid >> 4;           // 16 groups, one row each per iter
    #pragma unroll
    for (int it = 0; it < 10; ++it) {
      const int row = it * 16 + g;
      const int tok = toks[row];
      const bool valid = (tok >= 0);
      float e[4];
      #pragma unroll
      for (int j = 0; j < 4; ++j) {
        const int idx = lg + 16 * j;
        e[j] = (valid && idx < EMB) ? emb[tok * EMB + idx] : 0.0f;
      }
      float ss = e[0]*e[0] + e[1]*e[1] + e[2]*e[2] + e[3]*e[3];
      ss = grp16_sum(ss);
      const float scale = 1.0f / fmaxf(sqrtf(ss), 1e-12f);
      #pragma unroll
      for (int j = 0; j < 4; ++j) {
        const float v = e[j] * scale;
        const __hip_bfloat16 h = __float2bfloat16(v);
        shi[row][lg + 16 * j] = h;
        slo[row][lg + 16 * j] = __float2bfloat16(v - __bfloat162float(h));
      }
    }
  }
  __syncthreads();

  // ---- phase 2: MFMA cosine tiles + RBF chain ----
  // wave w: qtile = w>>1 (16 queries), dhalf = w&1 (64 docs)
  const int lane = tid & 63;
  const int w = tid >> 6;
  const int qtile = w >> 1;
  const int dhalf = w & 1;
  const int col = lane & 15;          // C col = query within tile
  const int kgrp = lane >> 4;         // 0..3
  const int klane = kgrp * 8;

  const int qrow = qtile * 16 + col;
  const short8 Bh0 = *(const short8*)&shi[qrow][klane];
  const short8 Bh1 = *(const short8*)&shi[qrow][32 + klane];
  const short8 Bl0 = *(const short8*)&slo[qrow][klane];
  const short8 Bl1 = *(const short8*)&slo[qrow][32 + klane];
  const int qtok = toks[qrow];

  float racc[KN];
  #pragma unroll
  for (int k = 0; k < KN; ++k) racc[k] = 0.0f;
  float cnt = 0.0f;

  #pragma unroll
  for (int dt = 0; dt < 4; ++dt) {
    const int arow = 32 + dhalf * 64 + dt * 16 + col;   // A row = doc
    const short8 Ah0 = *(const short8*)&shi[arow][klane];
    const short8 Ah1 = *(const short8*)&shi[arow][32 + klane];
    const short8 Al0 = *(const short8*)&slo[arow][klane];
    const short8 Al1 = *(const short8*)&slo[arow][32 + klane];

    f32x4 acc = {0.0f, 0.0f, 0.0f, 0.0f};
    acc = __builtin_amdgcn_mfma_f32_16x16x32_bf16(Ah0, Bh0, acc, 0, 0, 0);
    acc = __builtin_amdgcn_mfma_f32_16x16x32_bf16(Ah1, Bh1, acc, 0, 0, 0);
    acc = __builtin_amdgcn_mfma_f32_16x16x32_bf16(Al0, Bh0, acc, 0, 0, 0);
    acc = __builtin_amdgcn_mfma_f32_16x16x32_bf16(Al1, Bh1, acc, 0, 0, 0);
    acc = __builtin_amdgcn_mfma_f32_16x16x32_bf16(Ah0, Bl0, acc, 0, 0, 0);
    acc = __builtin_amdgcn_mfma_f32_16x16x32_bf16(Ah1, Bl1, acc, 0, 0, 0);

    const int dbase = 32 + dhalf * 64 + dt * 16 + kgrp * 4; // C row = doc
    #pragma unroll
    for (int r = 0; r < 4; ++r) {
      const float x = acc[r];
      cnt += (toks[dbase + r] == qtok) ? 1.0f : 0.0f;  // exact-match kernel
      // 20 smooth RBF kernels via two-sided ratio chain from mu=0.05
      const float t = x - 0.05f;
      const float v = __expf(-50.0f * t * t);
      const float E = __expf(10.0f * x);
      const float F = __expf(-10.0f * x);
      racc[10] += v;
      float vu = v, ru = E * EM1;
      #pragma unroll
      for (int k = 11; k <= 19; ++k) { vu *= ru; racc[k] += vu; ru *= EM1; }
      float vd = v, rd = F;
      #pragma unroll
      for (int k = 9; k >= 0; --k) { vd *= rd; racc[k] += vd; rd *= EM1; }
    }
  }
  racc[20] = cnt;

  // reduce over the 4 row-groups (docs) within the wave
  #pragma unroll
  for (int k = 0; k < KN; ++k) {
    racc[k] += __shfl_xor(racc[k], 16);
    racc[k] += __shfl_xor(racc[k], 32);
  }

  // cross-wave doc reduction: dhalf==1 waves stage, dhalf==0 waves combine
  if (dhalf == 1 && lane < 16) {
    #pragma unroll
    for (int k = 0; k < KN; ++k) redbuf[qtile][lane][k] = racc[k];
  }
  __syncthreads();

  float qval = 0.0f;
  if (dhalf == 0 && lane < 16) {
    const int q = qtile * 16 + lane;
    if (q < LQ) {
      float s = 0.0f;
      #pragma unroll
      for (int k = 0; k < KN; ++k) {
        const float S = racc[k] + redbuf[qtile][lane][k];
        s = fmaf(mlp_w[k], __logf(1.0f + S), s);
      }
      qval = s;
    }
  }
  qval += __shfl_xor(qval, 1);
  qval += __shfl_xor(qval, 2);
  qval += __shfl_xor(qval, 4);
  qval += __shfl_xor(qval, 8);
  if (dhalf == 0 && lane == 0) qpart[qtile] = qval;
  __syncthreads();
  if (tid == 0)
    logits[pair * BATCH + b] = qpart[0] + qpart[1] + mlp_b[0];
}

__global__ void knrm_combine_kernel(const float* __restrict__ logits,
                                    float* __restrict__ out) {
  int i = blockIdx.x * 256 + threadIdx.x;
  if (i < BATCH) {
    float z = logits[i] - logits[BATCH + i];
    out[i] = 1.0f / (1.0f + __expf(-z));
  }
}

extern "C" void kernel_launch(void* const* d_in, const int* in_sizes, int n_in,
                              void* d_out, int out_size, void* d_ws, size_t ws_size,
                              hipStream_t stream) {
  const int* q1 = (const int*)d_in[0];
  const int* d1 = (const int*)d_in[1];
  const int* q2 = (const int*)d_in[2];
  const int* d2 = (const int*)d_in[3];
  const float* emb = (const float*)d_in[4];
  const float* mlp_w = (const float*)d_in[5];
  const float* mlp_b = (const float*)d_in[6];
  float* out = (float*)d_out;
  float* logits = (float*)d_ws;   // 2*BATCH floats of scratch

  dim3 grid(BATCH, 2);
  knrm_pair_kernel<<<grid, 256, 0, stream>>>(q1, d1, q2, d2, emb, mlp_w, mlp_b, logits);
  knrm_combine_kernel<<<(BATCH + 255) / 256, 256, 0, stream>>>(logits, out);
}